// Round 23
// baseline (85.836 us; speedup 1.0000x reference)
//
#include <hip/hip_runtime.h>
#include <math.h>

#define G      32
#define NCELLS (G * G * G)        // 32768
#define TOTC   (2 * NCELLS)       // ref cells + query cells
#define LOF    (-6.0f)
#define HH     0.375f             // 12/32
#define INVH   (1.0f / 0.375f)
#define DELTA  1e-3f              // accept slack >> fp d2 rounding (~1e-5)
#define R2ACC  (HH * HH)
#define R2ACC5 (4.0f * HH * HH)   // knn125 accept radius^2 (2h)^2
#define SCB    256                // scan blocks (TOTC / 256)
#define SCC    (TOTC / SCB)       // 256 cells per scan block

__device__ __forceinline__ int cell_coord(float x) {
    int c = (int)floorf((x - LOF) * INVH);
    c = c < 0 ? 0 : c;
    return c > G - 1 ? G - 1 : c;
}
__device__ __forceinline__ int imax2(int a, int b) { return a > b ? a : b; }
__device__ __forceinline__ int imin2(int a, int b) { return a < b ? a : b; }
__device__ __forceinline__ float rdfl(float v) {
    return __int_as_float(__builtin_amdgcn_readfirstlane(__float_as_int(v)));
}

// lexicographic (d, idx) 3-slot insert == jax top_k tie semantics (order-free)
#define LEXINSERT(dv, jv) do {                                        \
    float d_ = (dv); int j_ = (jv);                                   \
    bool l0 = (d_ < e0) || ((d_ == e0) && (j_ < i0));                 \
    bool l1 = (d_ < e1) || ((d_ == e1) && (j_ < i1));                 \
    bool l2 = (d_ < e2) || ((d_ == e2) && (j_ < i2));                 \
    int   ni0 = l0 ? j_ : i0;                                         \
    int   ni1 = l0 ? i0 : (l1 ? j_ : i1);                             \
    int   ni2 = l1 ? i1 : (l2 ? j_ : i2);                             \
    float ne0 = l0 ? d_ : e0;                                         \
    float ne1 = l0 ? e0 : (l1 ? d_ : e1);                             \
    float ne2 = l1 ? e1 : (l2 ? d_ : e2);                             \
    e0 = ne0; e1 = ne1; e2 = ne2; i0 = ni0; i1 = ni1; i2 = ni2;       \
} while (0)

// lanes split refs [lo,hi) of a contiguous run; coalesced float4 loads.
// unroll 4 keeps 4 loads in flight (rolled loop waits vmcnt(0) per body).
#define SCAN_RUN(lo_, hi_) do {                                       \
    _Pragma("unroll 4")                                               \
    for (int u = (lo_) + lane; u < (hi_); u += 64) {                  \
        float4 rr = srt[u];                                           \
        float xx = rr.x * rr.x;                                       \
        float yy = rr.y * rr.y;                                       \
        float zz = rr.z * rr.z;                                       \
        float r2 = (xx + yy) + zz;                                    \
        float td = qx * rr.x;                                         \
        td = fmaf(qy, rr.y, td);                                      \
        td = fmaf(qz, rr.z, td);                                      \
        float aa = q2 + r2;                                           \
        float dd = fmaf(-2.0f, td, aa);                               \
        int jj = __float_as_int(rr.w);                                \
        LEXINSERT(dd, jj);                                            \
    }                                                                 \
} while (0)

// 64-lane butterfly lex-merge of per-lane top-3 sets
#define MERGE64() do {                                                \
    _Pragma("unroll")                                                 \
    for (int mk_ = 1; mk_ < 64; mk_ <<= 1) {                          \
        float f0 = __shfl_xor(e0, mk_, 64);                           \
        float f1 = __shfl_xor(e1, mk_, 64);                           \
        float f2 = __shfl_xor(e2, mk_, 64);                           \
        int   g0 = __shfl_xor(i0, mk_, 64);                           \
        int   g1 = __shfl_xor(i1, mk_, 64);                           \
        int   g2 = __shfl_xor(i2, mk_, 64);                           \
        LEXINSERT(f0, g0);                                            \
        LEXINSERT(f1, g1);                                            \
        LEXINSERT(f2, g2);                                            \
    }                                                                 \
} while (0)

// 32-lane butterfly: both queries of the wave share the instructions
#define MERGE32() do {                                                \
    _Pragma("unroll")                                                 \
    for (int mk_ = 1; mk_ < 32; mk_ <<= 1) {                          \
        float f0 = __shfl_xor(e0, mk_, 64);                           \
        float f1 = __shfl_xor(e1, mk_, 64);                           \
        float f2 = __shfl_xor(e2, mk_, 64);                           \
        int   g0 = __shfl_xor(i0, mk_, 64);                           \
        int   g1 = __shfl_xor(i1, mk_, 64);                           \
        int   g2 = __shfl_xor(i2, mk_, 64);                           \
        LEXINSERT(f0, g0);                                            \
        LEXINSERT(f1, g1);                                            \
        LEXINSERT(f2, g2);                                            \
    }                                                                 \
} while (0)

// clamp + weights + gather + store, reference op order
#define EPILOGUE() do {                                               \
    e0 = fmaxf(e0, 0.0f);                                             \
    e1 = fmaxf(e1, 0.0f);                                             \
    e2 = fmaxf(e2, 0.0f);                                             \
    float s0 = sqrtf(e0);                                             \
    float s1 = sqrtf(e1);                                             \
    float s2 = sqrtf(e2);                                             \
    float w0 = 1.0f / (s0 + 1e-8f);                                   \
    float w1 = 1.0f / (s1 + 1e-8f);                                   \
    float w2 = 1.0f / (s2 + 1e-8f);                                   \
    float wsum = (w0 + w1) + w2;                                      \
    w0 = w0 / wsum; w1 = w1 / wsum; w2 = w2 / wsum;                   \
    float f0x = flow[i0*3+0], f0y = flow[i0*3+1], f0z = flow[i0*3+2]; \
    float f1x = flow[i1*3+0], f1y = flow[i1*3+1], f1z = flow[i1*3+2]; \
    float f2x = flow[i2*3+0], f2y = flow[i2*3+1], f2z = flow[i2*3+2]; \
    out[q*3+0] = (w0 * f0x + w1 * f1x) + w2 * f2x;                    \
    out[q*3+1] = (w0 * f0y + w1 * f1y) + w2 * f2y;                    \
    out[q*3+2] = (w0 * f0z + w1 * f1z) + w2 * f2z;                    \
} while (0)

__global__ __launch_bounds__(256) void zero_ints(int* __restrict__ p, int n) {
    int i = blockIdx.x * 256 + threadIdx.x;
    if (i < n) p[i] = 0;
}

// fused count: refs into cells [0,NCELLS), queries into [NCELLS, TOTC)
__global__ __launch_bounds__(256) void bin_count2(
    const float* __restrict__ ref, const float* __restrict__ qpts,
    int* __restrict__ cnt, int Nr, int Nq) {
    int j = blockIdx.x * 256 + threadIdx.x;
    if (j < Nr) {
        int cx = cell_coord(ref[3 * j + 0]);
        int cy = cell_coord(ref[3 * j + 1]);
        int cz = cell_coord(ref[3 * j + 2]);
        atomicAdd(&cnt[(cz * G + cy) * G + cx], 1);
    } else if (j < Nr + Nq) {
        int k = j - Nr;
        int cx = cell_coord(qpts[3 * k + 0]);
        int cy = cell_coord(qpts[3 * k + 1]);
        int cz = cell_coord(qpts[3 * k + 2]);
        atomicAdd(&cnt[NCELLS + (cz * G + cy) * G + cx], 1);
    }
}

// parallel hierarchical scan over TOTC cells (R20-proven structure)
__global__ __launch_bounds__(256) void scan1(
    const int* __restrict__ cnt, int* __restrict__ off, int* __restrict__ bsum) {
    __shared__ int wt[4];
    int tid = threadIdx.x, b = blockIdx.x;
    int base = b * SCC;
    int lane = tid & 63, wid = tid >> 6;
    int v = cnt[base + tid];
    int incl = v;
#pragma unroll
    for (int sh = 1; sh < 64; sh <<= 1) {
        int t = __shfl_up(incl, sh, 64);
        if (lane >= sh) incl += t;
    }
    if (lane == 63) wt[wid] = incl;
    __syncthreads();
    if (tid == 0) {
        int run = 0;
#pragma unroll
        for (int w = 0; w < 4; ++w) { int t = wt[w]; wt[w] = run; run += t; }
    }
    __syncthreads();
    int excl = wt[wid] + incl - v;
    off[base + tid] = excl;
    if (tid == SCC - 1) bsum[b] = excl + v;
}

// scan2 also zeroes both flag counters (block 0)
__global__ __launch_bounds__(256) void scan2(
    const int* __restrict__ bsum, int* __restrict__ off, int* __restrict__ cur,
    int* __restrict__ nflag) {
    __shared__ int red[4];
    __shared__ int bo;
    int tid = threadIdx.x, b = blockIdx.x;
    int lane = tid & 63, wid = tid >> 6;
    if (b == 0 && tid < 2) nflag[tid] = 0;
    int m = (tid < b) ? bsum[tid] : 0;             // b < SCB == 256
#pragma unroll
    for (int mk = 1; mk < 64; mk <<= 1) m += __shfl_xor(m, mk, 64);
    if (lane == 0) red[wid] = m;
    __syncthreads();
    if (tid == 0) bo = red[0] + red[1] + red[2] + red[3];
    __syncthreads();
    int boff = bo;
    int base = b * SCC;
    int t = off[base + tid] + boff;
    off[base + tid] = t;
    cur[base + tid] = t;
    if (b == SCB - 1 && tid == SCC - 1) off[TOTC] = boff + bsum[b];
}

// fused scatter: refs into big[0..Nr); queries into big[Nr..Nr+Nq)
__global__ __launch_bounds__(256) void bin_fill2(
    const float* __restrict__ ref, const float* __restrict__ qpts,
    int* __restrict__ cur, float4* __restrict__ big, int Nr, int Nq) {
    int j = blockIdx.x * 256 + threadIdx.x;
    if (j < Nr) {
        float x = ref[3 * j + 0], y = ref[3 * j + 1], z = ref[3 * j + 2];
        int cell = (cell_coord(z) * G + cell_coord(y)) * G + cell_coord(x);
        int pos = atomicAdd(&cur[cell], 1);
        big[pos] = make_float4(x, y, z, __int_as_float(j));
    } else if (j < Nr + Nq) {
        int k = j - Nr;
        float x = qpts[3 * k + 0], y = qpts[3 * k + 1], z = qpts[3 * k + 2];
        int cell = NCELLS + (cell_coord(z) * G + cell_coord(y)) * G + cell_coord(x);
        int pos = atomicAdd(&cur[cell], 1);
        big[pos] = make_float4(x, y, z, __int_as_float(k));
    }
}

// u -> srt index via the proven 9-row bijection (p*, b* group-uniform)
#define MAPIDX(u_, out_) do {                                         \
    int t_ = (u_) + b0;                                               \
    t_ = ((u_) >= p1) ? ((u_) + b1) : t_;                             \
    t_ = ((u_) >= p2) ? ((u_) + b2) : t_;                             \
    t_ = ((u_) >= p3) ? ((u_) + b3) : t_;                             \
    t_ = ((u_) >= p4) ? ((u_) + b4) : t_;                             \
    t_ = ((u_) >= p5) ? ((u_) + b5) : t_;                             \
    t_ = ((u_) >= p6) ? ((u_) + b6) : t_;                             \
    t_ = ((u_) >= p7) ? ((u_) + b7) : t_;                             \
    t_ = ((u_) >= p8) ? ((u_) + b8) : t_;                             \
    (out_) = t_;                                                      \
} while (0)

// d2 compute + insert for one loaded float4 (bit-identical chain)
#define BODY(rr_) do {                                                \
    float xx = (rr_).x * (rr_).x;                                     \
    float yy = (rr_).y * (rr_).y;                                     \
    float zz = (rr_).z * (rr_).z;                                     \
    float r2v = (xx + yy) + zz;                                       \
    float td = qx * (rr_).x;                                          \
    td = fmaf(qy, (rr_).y, td);                                       \
    td = fmaf(qz, (rr_).z, td);                                       \
    float aa = q2 + r2v;                                              \
    float dd = fmaf(-2.0f, td, aa);                                   \
    int jj = __float_as_int((rr_).w);                                 \
    LEXINSERT(dd, jj);                                                \
} while (0)

// ---------------------------------------------------------------------------
// 27-cell kNN over spatially sorted queries (R21/R22-passing verbatim).
// ---------------------------------------------------------------------------
__global__ __launch_bounds__(256) void knn27(
    const float4* __restrict__ big, const int* __restrict__ off,
    const float* __restrict__ flow, float* __restrict__ out,
    int* __restrict__ qlist, int* __restrict__ nflag, int Nr, int Nq) {
#pragma clang fp contract(off)
    const float4* __restrict__ srt = big;          // refs region
    int sl = threadIdx.x & 31;                     // sub-lane in 32-group
    int sq = blockIdx.x * 8 + (threadIdx.x >> 5);  // sorted query index
    bool qv = sq < Nq;
    int sqc = qv ? sq : 0;

    float4 qq = big[(size_t)Nr + sqc];             // broadcast across group
    float qx = qq.x, qy = qq.y, qz = qq.z;
    int   q  = __float_as_int(qq.w);               // original query index
    float q2 = (qx * qx + qy * qy) + qz * qz;

    int cx = cell_coord(qx), cy = cell_coord(qy), cz = cell_coord(qz);

    int dz = sl / 3 - 1, dy = sl % 3 - 1;          // meaningful for sl<9
    int zr = cz + dz, yr = cy + dy;
    bool vrow = (sl < 9) && qv && (zr >= 0) && (zr < G) && (yr >= 0) && (yr < G);
    int xlo = imax2(cx - 1, 0), xhi = imin2(cx + 1, G - 1);
    int vlo = 0, vhi = 0;
    if (vrow) {
        int rowbase = (zr * G + yr) * G;
        vlo = off[rowbase + xlo];
        vhi = off[rowbase + xhi + 1];
    }
    int cnt = vhi - vlo;

    int incl = cnt;
#pragma unroll
    for (int sh = 1; sh <= 8; sh <<= 1) {
        int t = __shfl_up(incl, sh, 32);
        if (sl >= sh) incl += t;
    }
    int total = __shfl(incl, 8, 32);
    int prex  = incl - cnt;

    int p1 = __shfl(prex, 1, 32), p2 = __shfl(prex, 2, 32);
    int p3 = __shfl(prex, 3, 32), p4 = __shfl(prex, 4, 32);
    int p5 = __shfl(prex, 5, 32), p6 = __shfl(prex, 6, 32);
    int p7 = __shfl(prex, 7, 32), p8 = __shfl(prex, 8, 32);
    int b0 = __shfl(vlo, 0, 32);
    int b1 = __shfl(vlo, 1, 32) - p1;
    int b2 = __shfl(vlo, 2, 32) - p2;
    int b3 = __shfl(vlo, 3, 32) - p3;
    int b4 = __shfl(vlo, 4, 32) - p4;
    int b5 = __shfl(vlo, 5, 32) - p5;
    int b6 = __shfl(vlo, 6, 32) - p6;
    int b7 = __shfl(vlo, 7, 32) - p7;
    int b8 = __shfl(vlo, 8, 32) - p8;

    const float FINF = __builtin_inff();
    float e0 = FINF, e1 = FINF, e2 = FINF;
    int   i0 = 0x7fffffff, i1 = 0x7fffffff, i2 = 0x7fffffff;

    int u = sl;
    if (u < total) {
        int idx;
        MAPIDX(u, idx);
        float4 rr = srt[idx];
        for (u += 32; u < total; u += 32) {
            int idx2;
            MAPIDX(u, idx2);
            float4 rn = srt[idx2];
            BODY(rr);
            rr = rn;
        }
        BODY(rr);
    }

    MERGE32();

    bool ok = (e2 + DELTA < R2ACC);
    if (sl == 0 && qv) {
        if (ok) {
            EPILOGUE();
        } else {
            int pos = atomicAdd(&nflag[0], 1);
            qlist[pos] = q;                        // original index
        }
    }
}

// ---------------------------------------------------------------------------
// Level 2 (R17/R18-proven): 5x5x5 neighborhood, one wave per flagged query,
// grid-strided. Guarantee radius 2h; accept iff e2_raw + DELTA < (2h)^2.
// Residual (~0.1% of all queries) appended to qlist2.
// ---------------------------------------------------------------------------
__global__ __launch_bounds__(256) void knn125(
    const float* __restrict__ qpts, const float4* __restrict__ srt,
    const int* __restrict__ off, const int* __restrict__ qlist,
    const int* __restrict__ nflag, const float* __restrict__ flow,
    float* __restrict__ out, int* __restrict__ qlist2,
    int* __restrict__ nflag2) {
#pragma clang fp contract(off)
    int lane = threadIdx.x & 63;
    int wav  = (blockIdx.x * 256 + threadIdx.x) >> 6;
    int nWaves = (gridDim.x * 256) >> 6;
    int n = nflag[0];

    for (int f = wav; f < n; f += nWaves) {
        int q = qlist[f];
        float qx = rdfl(qpts[3 * q + 0]);
        float qy = rdfl(qpts[3 * q + 1]);
        float qz = rdfl(qpts[3 * q + 2]);
        float q2 = (qx * qx + qy * qy) + qz * qz;

        int cx = cell_coord(qx), cy = cell_coord(qy), cz = cell_coord(qz);

        // 25 row bounds fetched in parallel by lanes 0..24
        int dz = lane / 5 - 2, dy = lane % 5 - 2;  // meaningful for lane<25
        int zr = cz + dz, yr = cy + dy;
        bool vrow = (lane < 25) && (zr >= 0) && (zr < G) && (yr >= 0) && (yr < G);
        int xlo = imax2(cx - 2, 0), xhi = imin2(cx + 2, G - 1);
        int vlo = 0, vhi = 0;
        if (vrow) {
            int rowbase = (zr * G + yr) * G;
            vlo = off[rowbase + xlo];
            vhi = off[rowbase + xhi + 1];
        }

        const float FINF = __builtin_inff();
        float e0 = FINF, e1 = FINF, e2 = FINF;
        int   i0 = 0x7fffffff, i1 = 0x7fffffff, i2 = 0x7fffffff;

#pragma unroll
        for (int r = 0; r < 25; ++r) {
            int lo = __shfl(vlo, r, 64);
            int hi = __shfl(vhi, r, 64);
            SCAN_RUN(lo, hi);
        }

        MERGE64();                                 // raw (unclamped) merge

        bool ok = (e2 + DELTA < R2ACC5);           // INF -> fail
        if (lane == 0) {
            if (ok) {
                EPILOGUE();
            } else {
                int pos = atomicAdd(nflag2, 1);
                qlist2[pos] = q;
            }
        }
    }
}

// ---------------------------------------------------------------------------
// Final brute (exactness safety net, ~15 queries): one block (4 waves) per
// residual query; unrolled coalesced scan; LDS cross-wave merge; epilogue.
// ---------------------------------------------------------------------------
__global__ __launch_bounds__(256) void brute_block(
    const float* __restrict__ qpts, const float4* __restrict__ srt,
    const int* __restrict__ qlist2, const int* __restrict__ nflag2,
    const float* __restrict__ flow, float* __restrict__ out, int Nr) {
#pragma clang fp contract(off)
    __shared__ float sd[12];
    __shared__ int   si[12];
    int tid = threadIdx.x;
    int lane = tid & 63, wv = tid >> 6;
    int n = nflag2[0];

    for (int f = blockIdx.x; f < n; f += gridDim.x) {
        int q = qlist2[f];
        float qx = rdfl(qpts[3 * q + 0]);
        float qy = rdfl(qpts[3 * q + 1]);
        float qz = rdfl(qpts[3 * q + 2]);
        float q2 = (qx * qx + qy * qy) + qz * qz;

        int CS = (Nr + 3) / 4;
        int lo = wv * CS;
        int hi = imin2(lo + CS, Nr);

        const float FINF = __builtin_inff();
        float e0 = FINF, e1 = FINF, e2 = FINF;
        int   i0 = 0x7fffffff, i1 = 0x7fffffff, i2 = 0x7fffffff;

        SCAN_RUN(lo, hi);
        MERGE64();

        if (lane == 0) {
            sd[wv * 3 + 0] = e0; si[wv * 3 + 0] = i0;
            sd[wv * 3 + 1] = e1; si[wv * 3 + 1] = i1;
            sd[wv * 3 + 2] = e2; si[wv * 3 + 2] = i2;
        }
        __syncthreads();
        if (wv == 0) {
            e0 = e1 = e2 = FINF;
            i0 = i1 = i2 = 0x7fffffff;
            if (lane < 12) { e0 = sd[lane]; i0 = si[lane]; }
            MERGE64();
            if (lane == 0) EPILOGUE();
        }
        __syncthreads();
    }
}

extern "C" void kernel_launch(void* const* d_in, const int* in_sizes, int n_in,
                              void* d_out, int out_size, void* d_ws, size_t ws_size,
                              hipStream_t stream) {
    const float* qp   = (const float*)d_in[0];
    const float* ref  = (const float*)d_in[1];
    const float* flow = (const float*)d_in[2];
    float* out = (float*)d_out;

    int Nq = in_sizes[0] / 3;
    int Nr = in_sizes[1] / 3;

    char* ws = (char*)d_ws;
    float4* big = (float4*)ws;                       // (Nr+Nq) float4
    size_t o = (size_t)(Nr + Nq) * sizeof(float4);
    int* off    = (int*)(ws + o);  o += (size_t)(TOTC + 1) * sizeof(int);
    int* cur    = (int*)(ws + o);  o += (size_t)TOTC * sizeof(int);
    int* cnt    = (int*)(ws + o);  o += (size_t)TOTC * sizeof(int);
    int* nflag  = (int*)(ws + o);  o += 2 * sizeof(int); // [0]=L1 fail, [1]=L2 fail
    int* nflag2 = nflag + 1;
    int* qlist  = (int*)(ws + o);  o += (size_t)Nq * sizeof(int);
    int* qlist2 = (int*)(ws + o);  o += (size_t)Nq * sizeof(int);
    int* bsum   = (int*)(ws + o);  o += (size_t)SCB * sizeof(int);

    zero_ints<<<(TOTC + 255) / 256, 256, 0, stream>>>(cnt, TOTC);
    bin_count2<<<(Nr + Nq + 255) / 256, 256, 0, stream>>>(ref, qp, cnt, Nr, Nq);
    scan1<<<SCB, 256, 0, stream>>>(cnt, off, bsum);
    scan2<<<SCB, 256, 0, stream>>>(bsum, off, cur, nflag);
    bin_fill2<<<(Nr + Nq + 255) / 256, 256, 0, stream>>>(ref, qp, cur, big, Nr, Nq);

    int nBlocks = (Nq + 7) / 8;                      // 8 sorted queries/block
    knn27<<<nBlocks, 256, 0, stream>>>(big, off, flow, out, qlist, nflag, Nr, Nq);
    knn125<<<1024, 256, 0, stream>>>(qp, big, off, qlist, nflag, flow, out,
                                     qlist2, nflag2);
    brute_block<<<256, 256, 0, stream>>>(qp, big, qlist2, nflag2, flow, out, Nr);
}

// Round 24
// 67.855 us; speedup vs baseline: 1.2650x; 1.2650x over previous
//
#include <hip/hip_runtime.h>
#include <math.h>

#define G      32
#define NCELLS (G * G * G)        // 32768
#define TOTC   (2 * NCELLS)       // ref cells + query cells
#define LOF    (-6.0f)
#define HH     0.375f             // 12/32
#define INVH   (1.0f / 0.375f)
#define DELTA  1e-3f              // accept slack >> fp d2 rounding (~1e-5)
#define R2ACC  (HH * HH)
#define SCB    256                // scan blocks (TOTC / 256)
#define SCC    (TOTC / SCB)       // 256 cells per scan block

__device__ __forceinline__ int cell_coord(float x) {
    int c = (int)floorf((x - LOF) * INVH);
    c = c < 0 ? 0 : c;
    return c > G - 1 ? G - 1 : c;
}
__device__ __forceinline__ int imax2(int a, int b) { return a > b ? a : b; }
__device__ __forceinline__ int imin2(int a, int b) { return a < b ? a : b; }
__device__ __forceinline__ float rdfl(float v) {
    return __int_as_float(__builtin_amdgcn_readfirstlane(__float_as_int(v)));
}

// lexicographic (d, idx) 3-slot insert == jax top_k tie semantics (order-free)
#define LEXINSERT(dv, jv) do {                                        \
    float d_ = (dv); int j_ = (jv);                                   \
    bool l0 = (d_ < e0) || ((d_ == e0) && (j_ < i0));                 \
    bool l1 = (d_ < e1) || ((d_ == e1) && (j_ < i1));                 \
    bool l2 = (d_ < e2) || ((d_ == e2) && (j_ < i2));                 \
    int   ni0 = l0 ? j_ : i0;                                         \
    int   ni1 = l0 ? i0 : (l1 ? j_ : i1);                             \
    int   ni2 = l1 ? i1 : (l2 ? j_ : i2);                             \
    float ne0 = l0 ? d_ : e0;                                         \
    float ne1 = l0 ? e0 : (l1 ? d_ : e1);                             \
    float ne2 = l1 ? e1 : (l2 ? d_ : e2);                             \
    e0 = ne0; e1 = ne1; e2 = ne2; i0 = ni0; i1 = ni1; i2 = ni2;       \
} while (0)

// lanes split refs [lo,hi) of a contiguous run; coalesced float4 loads.
#define SCAN_RUN(lo_, hi_) do {                                       \
    for (int u = (lo_) + lane; u < (hi_); u += 64) {                  \
        float4 rr = srt[u];                                           \
        float xx = rr.x * rr.x;                                       \
        float yy = rr.y * rr.y;                                       \
        float zz = rr.z * rr.z;                                       \
        float r2 = (xx + yy) + zz;                                    \
        float td = qx * rr.x;                                         \
        td = fmaf(qy, rr.y, td);                                      \
        td = fmaf(qz, rr.z, td);                                      \
        float aa = q2 + r2;                                           \
        float dd = fmaf(-2.0f, td, aa);                               \
        int jj = __float_as_int(rr.w);                                \
        LEXINSERT(dd, jj);                                            \
    }                                                                 \
} while (0)

// 64-lane butterfly lex-merge of per-lane top-3 sets
#define MERGE64() do {                                                \
    _Pragma("unroll")                                                 \
    for (int mk_ = 1; mk_ < 64; mk_ <<= 1) {                          \
        float f0 = __shfl_xor(e0, mk_, 64);                           \
        float f1 = __shfl_xor(e1, mk_, 64);                           \
        float f2 = __shfl_xor(e2, mk_, 64);                           \
        int   g0 = __shfl_xor(i0, mk_, 64);                           \
        int   g1 = __shfl_xor(i1, mk_, 64);                           \
        int   g2 = __shfl_xor(i2, mk_, 64);                           \
        LEXINSERT(f0, g0);                                            \
        LEXINSERT(f1, g1);                                            \
        LEXINSERT(f2, g2);                                            \
    }                                                                 \
} while (0)

// 32-lane butterfly: both queries of the wave share the instructions
#define MERGE32() do {                                                \
    _Pragma("unroll")                                                 \
    for (int mk_ = 1; mk_ < 32; mk_ <<= 1) {                          \
        float f0 = __shfl_xor(e0, mk_, 64);                           \
        float f1 = __shfl_xor(e1, mk_, 64);                           \
        float f2 = __shfl_xor(e2, mk_, 64);                           \
        int   g0 = __shfl_xor(i0, mk_, 64);                           \
        int   g1 = __shfl_xor(i1, mk_, 64);                           \
        int   g2 = __shfl_xor(i2, mk_, 64);                           \
        LEXINSERT(f0, g0);                                            \
        LEXINSERT(f1, g1);                                            \
        LEXINSERT(f2, g2);                                            \
    }                                                                 \
} while (0)

// clamp + weights + gather + store, reference op order
#define EPILOGUE() do {                                               \
    e0 = fmaxf(e0, 0.0f);                                             \
    e1 = fmaxf(e1, 0.0f);                                             \
    e2 = fmaxf(e2, 0.0f);                                             \
    float s0 = sqrtf(e0);                                             \
    float s1 = sqrtf(e1);                                             \
    float s2 = sqrtf(e2);                                             \
    float w0 = 1.0f / (s0 + 1e-8f);                                   \
    float w1 = 1.0f / (s1 + 1e-8f);                                   \
    float w2 = 1.0f / (s2 + 1e-8f);                                   \
    float wsum = (w0 + w1) + w2;                                      \
    w0 = w0 / wsum; w1 = w1 / wsum; w2 = w2 / wsum;                   \
    float f0x = flow[i0*3+0], f0y = flow[i0*3+1], f0z = flow[i0*3+2]; \
    float f1x = flow[i1*3+0], f1y = flow[i1*3+1], f1z = flow[i1*3+2]; \
    float f2x = flow[i2*3+0], f2y = flow[i2*3+1], f2z = flow[i2*3+2]; \
    out[q*3+0] = (w0 * f0x + w1 * f1x) + w2 * f2x;                    \
    out[q*3+1] = (w0 * f0y + w1 * f1y) + w2 * f2y;                    \
    out[q*3+2] = (w0 * f0z + w1 * f1z) + w2 * f2z;                    \
} while (0)

__global__ __launch_bounds__(256) void zero_ints(int* __restrict__ p, int n) {
    int i = blockIdx.x * 256 + threadIdx.x;
    if (i < n) p[i] = 0;
}

// fused count: refs into cells [0,NCELLS), queries into [NCELLS, TOTC)
__global__ __launch_bounds__(256) void bin_count2(
    const float* __restrict__ ref, const float* __restrict__ qpts,
    int* __restrict__ cnt, int Nr, int Nq) {
    int j = blockIdx.x * 256 + threadIdx.x;
    if (j < Nr) {
        int cx = cell_coord(ref[3 * j + 0]);
        int cy = cell_coord(ref[3 * j + 1]);
        int cz = cell_coord(ref[3 * j + 2]);
        atomicAdd(&cnt[(cz * G + cy) * G + cx], 1);
    } else if (j < Nr + Nq) {
        int k = j - Nr;
        int cx = cell_coord(qpts[3 * k + 0]);
        int cy = cell_coord(qpts[3 * k + 1]);
        int cz = cell_coord(qpts[3 * k + 2]);
        atomicAdd(&cnt[NCELLS + (cz * G + cy) * G + cx], 1);
    }
}

// parallel hierarchical scan over TOTC cells (R20-proven structure)
__global__ __launch_bounds__(256) void scan1(
    const int* __restrict__ cnt, int* __restrict__ off, int* __restrict__ bsum) {
    __shared__ int wt[4];
    int tid = threadIdx.x, b = blockIdx.x;
    int base = b * SCC;
    int lane = tid & 63, wid = tid >> 6;
    int v = cnt[base + tid];
    int incl = v;
#pragma unroll
    for (int sh = 1; sh < 64; sh <<= 1) {
        int t = __shfl_up(incl, sh, 64);
        if (lane >= sh) incl += t;
    }
    if (lane == 63) wt[wid] = incl;
    __syncthreads();
    if (tid == 0) {
        int run = 0;
#pragma unroll
        for (int w = 0; w < 4; ++w) { int t = wt[w]; wt[w] = run; run += t; }
    }
    __syncthreads();
    int excl = wt[wid] + incl - v;
    off[base + tid] = excl;
    if (tid == SCC - 1) bsum[b] = excl + v;
}

// scan2 also zeroes the nflag counter (block 0)
__global__ __launch_bounds__(256) void scan2(
    const int* __restrict__ bsum, int* __restrict__ off, int* __restrict__ cur,
    int* __restrict__ nflag) {
    __shared__ int red[4];
    __shared__ int bo;
    int tid = threadIdx.x, b = blockIdx.x;
    int lane = tid & 63, wid = tid >> 6;
    if (b == 0 && tid == 0) nflag[0] = 0;
    int m = (tid < b) ? bsum[tid] : 0;             // b < SCB == 256
#pragma unroll
    for (int mk = 1; mk < 64; mk <<= 1) m += __shfl_xor(m, mk, 64);
    if (lane == 0) red[wid] = m;
    __syncthreads();
    if (tid == 0) bo = red[0] + red[1] + red[2] + red[3];
    __syncthreads();
    int boff = bo;
    int base = b * SCC;
    int t = off[base + tid] + boff;
    off[base + tid] = t;
    cur[base + tid] = t;
    if (b == SCB - 1 && tid == SCC - 1) off[TOTC] = boff + bsum[b];
}

// fused scatter: refs into big[0..Nr); queries into big[Nr..Nr+Nq)
__global__ __launch_bounds__(256) void bin_fill2(
    const float* __restrict__ ref, const float* __restrict__ qpts,
    int* __restrict__ cur, float4* __restrict__ big, int Nr, int Nq) {
    int j = blockIdx.x * 256 + threadIdx.x;
    if (j < Nr) {
        float x = ref[3 * j + 0], y = ref[3 * j + 1], z = ref[3 * j + 2];
        int cell = (cell_coord(z) * G + cell_coord(y)) * G + cell_coord(x);
        int pos = atomicAdd(&cur[cell], 1);
        big[pos] = make_float4(x, y, z, __int_as_float(j));
    } else if (j < Nr + Nq) {
        int k = j - Nr;
        float x = qpts[3 * k + 0], y = qpts[3 * k + 1], z = qpts[3 * k + 2];
        int cell = NCELLS + (cell_coord(z) * G + cell_coord(y)) * G + cell_coord(x);
        int pos = atomicAdd(&cur[cell], 1);
        big[pos] = make_float4(x, y, z, __int_as_float(k));
    }
}

// u -> srt index via the proven 9-row bijection (p*, b* group-uniform)
#define MAPIDX(u_, out_) do {                                         \
    int t_ = (u_) + b0;                                               \
    t_ = ((u_) >= p1) ? ((u_) + b1) : t_;                             \
    t_ = ((u_) >= p2) ? ((u_) + b2) : t_;                             \
    t_ = ((u_) >= p3) ? ((u_) + b3) : t_;                             \
    t_ = ((u_) >= p4) ? ((u_) + b4) : t_;                             \
    t_ = ((u_) >= p5) ? ((u_) + b5) : t_;                             \
    t_ = ((u_) >= p6) ? ((u_) + b6) : t_;                             \
    t_ = ((u_) >= p7) ? ((u_) + b7) : t_;                             \
    t_ = ((u_) >= p8) ? ((u_) + b8) : t_;                             \
    (out_) = t_;                                                      \
} while (0)

// d2 compute + insert for one loaded float4 (bit-identical chain)
#define BODY(rr_) do {                                                \
    float xx = (rr_).x * (rr_).x;                                     \
    float yy = (rr_).y * (rr_).y;                                     \
    float zz = (rr_).z * (rr_).z;                                     \
    float r2v = (xx + yy) + zz;                                       \
    float td = qx * (rr_).x;                                          \
    td = fmaf(qy, (rr_).y, td);                                       \
    td = fmaf(qz, (rr_).z, td);                                       \
    float aa = q2 + r2v;                                              \
    float dd = fmaf(-2.0f, td, aa);                                   \
    int jj = __float_as_int((rr_).w);                                 \
    LEXINSERT(dd, jj);                                                \
} while (0)

// ---------------------------------------------------------------------------
// 27-cell kNN over spatially sorted queries (R21/R22-passing verbatim).
// ---------------------------------------------------------------------------
__global__ __launch_bounds__(256) void knn27(
    const float4* __restrict__ big, const int* __restrict__ off,
    const float* __restrict__ flow, float* __restrict__ out,
    int* __restrict__ qlist, int* __restrict__ nflag, int Nr, int Nq) {
#pragma clang fp contract(off)
    const float4* __restrict__ srt = big;          // refs region
    int sl = threadIdx.x & 31;                     // sub-lane in 32-group
    int sq = blockIdx.x * 8 + (threadIdx.x >> 5);  // sorted query index
    bool qv = sq < Nq;
    int sqc = qv ? sq : 0;

    float4 qq = big[(size_t)Nr + sqc];             // broadcast across group
    float qx = qq.x, qy = qq.y, qz = qq.z;
    int   q  = __float_as_int(qq.w);               // original query index
    float q2 = (qx * qx + qy * qy) + qz * qz;

    int cx = cell_coord(qx), cy = cell_coord(qy), cz = cell_coord(qz);

    int dz = sl / 3 - 1, dy = sl % 3 - 1;          // meaningful for sl<9
    int zr = cz + dz, yr = cy + dy;
    bool vrow = (sl < 9) && qv && (zr >= 0) && (zr < G) && (yr >= 0) && (yr < G);
    int xlo = imax2(cx - 1, 0), xhi = imin2(cx + 1, G - 1);
    int vlo = 0, vhi = 0;
    if (vrow) {
        int rowbase = (zr * G + yr) * G;
        vlo = off[rowbase + xlo];
        vhi = off[rowbase + xhi + 1];
    }
    int cnt = vhi - vlo;

    int incl = cnt;
#pragma unroll
    for (int sh = 1; sh <= 8; sh <<= 1) {
        int t = __shfl_up(incl, sh, 32);
        if (sl >= sh) incl += t;
    }
    int total = __shfl(incl, 8, 32);
    int prex  = incl - cnt;

    int p1 = __shfl(prex, 1, 32), p2 = __shfl(prex, 2, 32);
    int p3 = __shfl(prex, 3, 32), p4 = __shfl(prex, 4, 32);
    int p5 = __shfl(prex, 5, 32), p6 = __shfl(prex, 6, 32);
    int p7 = __shfl(prex, 7, 32), p8 = __shfl(prex, 8, 32);
    int b0 = __shfl(vlo, 0, 32);
    int b1 = __shfl(vlo, 1, 32) - p1;
    int b2 = __shfl(vlo, 2, 32) - p2;
    int b3 = __shfl(vlo, 3, 32) - p3;
    int b4 = __shfl(vlo, 4, 32) - p4;
    int b5 = __shfl(vlo, 5, 32) - p5;
    int b6 = __shfl(vlo, 6, 32) - p6;
    int b7 = __shfl(vlo, 7, 32) - p7;
    int b8 = __shfl(vlo, 8, 32) - p8;

    const float FINF = __builtin_inff();
    float e0 = FINF, e1 = FINF, e2 = FINF;
    int   i0 = 0x7fffffff, i1 = 0x7fffffff, i2 = 0x7fffffff;

    int u = sl;
    if (u < total) {
        int idx;
        MAPIDX(u, idx);
        float4 rr = srt[idx];
        for (u += 32; u < total; u += 32) {
            int idx2;
            MAPIDX(u, idx2);
            float4 rn = srt[idx2];
            BODY(rr);
            rr = rn;
        }
        BODY(rr);
    }

    MERGE32();

    bool ok = (e2 + DELTA < R2ACC);
    if (sl == 0 && qv) {
        if (ok) {
            EPILOGUE();
        } else {
            int pos = atomicAdd(nflag, 1);
            qlist[pos] = q;                        // original index
        }
    }
}

// ---------------------------------------------------------------------------
// Brute fallback: ONE BLOCK (4 waves) per flagged query, MANUAL 4-deep
// pipeline (4 independent loads issued before 4 bodies) — keeps 4 loads in
// flight instead of the rolled loop's 1. Out-of-range slots get dd=INF,
// jj=INT_MAX (sentinel semantics; each wave has >=3 real refs so ghosts
// are always displaced). LDS cross-wave lex-merge; wave-0 epilogue.
// ---------------------------------------------------------------------------
__global__ __launch_bounds__(256) void brute_block(
    const float* __restrict__ qpts, const float4* __restrict__ srt,
    const int* __restrict__ qlist, const int* __restrict__ nflag,
    const float* __restrict__ flow, float* __restrict__ out, int Nr) {
#pragma clang fp contract(off)
    __shared__ float sd[12];
    __shared__ int   si[12];
    int tid = threadIdx.x;
    int lane = tid & 63, wv = tid >> 6;
    int n = nflag[0];

    for (int f = blockIdx.x; f < n; f += gridDim.x) {
        int q = qlist[f];
        float qx = rdfl(qpts[3 * q + 0]);
        float qy = rdfl(qpts[3 * q + 1]);
        float qz = rdfl(qpts[3 * q + 2]);
        float q2 = (qx * qx + qy * qy) + qz * qz;

        int CS = (Nr + 3) / 4;
        int lo = wv * CS;
        int hi = imin2(lo + CS, Nr);

        const float FINF = __builtin_inff();
        float e0 = FINF, e1 = FINF, e2 = FINF;
        int   i0 = 0x7fffffff, i1 = 0x7fffffff, i2 = 0x7fffffff;

        for (int ub = lo + lane; ub < hi; ub += 256) {
            int u0 = ub, u1 = ub + 64, u2 = ub + 128, u3 = ub + 192;
            // 4 independent loads issue together (clamped addr, masked later)
            float4 r0 = srt[imin2(u0, hi - 1)];
            float4 r1 = srt[imin2(u1, hi - 1)];
            float4 r2 = srt[imin2(u2, hi - 1)];
            float4 r3 = srt[imin2(u3, hi - 1)];
#define PBODY(rr_, uu_) do {                                          \
            float xx = (rr_).x * (rr_).x;                             \
            float yy = (rr_).y * (rr_).y;                             \
            float zz = (rr_).z * (rr_).z;                             \
            float r2v = (xx + yy) + zz;                               \
            float td = qx * (rr_).x;                                  \
            td = fmaf(qy, (rr_).y, td);                               \
            td = fmaf(qz, (rr_).z, td);                               \
            float aa = q2 + r2v;                                      \
            float dd = fmaf(-2.0f, td, aa);                           \
            bool in_ = (uu_) < hi;                                    \
            dd = in_ ? dd : FINF;                                     \
            int jj = in_ ? __float_as_int((rr_).w) : 0x7fffffff;      \
            LEXINSERT(dd, jj);                                        \
} while (0)
            PBODY(r0, u0);
            PBODY(r1, u1);
            PBODY(r2, u2);
            PBODY(r3, u3);
#undef PBODY
        }

        MERGE64();

        if (lane == 0) {
            sd[wv * 3 + 0] = e0; si[wv * 3 + 0] = i0;
            sd[wv * 3 + 1] = e1; si[wv * 3 + 1] = i1;
            sd[wv * 3 + 2] = e2; si[wv * 3 + 2] = i2;
        }
        __syncthreads();
        if (wv == 0) {
            e0 = e1 = e2 = FINF;
            i0 = i1 = i2 = 0x7fffffff;
            if (lane < 12) { e0 = sd[lane]; i0 = si[lane]; }
            MERGE64();
            if (lane == 0) EPILOGUE();
        }
        __syncthreads();
    }
}

extern "C" void kernel_launch(void* const* d_in, const int* in_sizes, int n_in,
                              void* d_out, int out_size, void* d_ws, size_t ws_size,
                              hipStream_t stream) {
    const float* qp   = (const float*)d_in[0];
    const float* ref  = (const float*)d_in[1];
    const float* flow = (const float*)d_in[2];
    float* out = (float*)d_out;

    int Nq = in_sizes[0] / 3;
    int Nr = in_sizes[1] / 3;

    char* ws = (char*)d_ws;
    float4* big = (float4*)ws;                       // (Nr+Nq) float4
    size_t o = (size_t)(Nr + Nq) * sizeof(float4);
    int* off    = (int*)(ws + o);  o += (size_t)(TOTC + 1) * sizeof(int);
    int* cur    = (int*)(ws + o);  o += (size_t)TOTC * sizeof(int);
    int* cnt    = (int*)(ws + o);  o += (size_t)TOTC * sizeof(int);
    int* nflag  = (int*)(ws + o);  o += sizeof(int); // zeroed by scan2
    int* qlist  = (int*)(ws + o);  o += (size_t)Nq * sizeof(int);
    int* bsum   = (int*)(ws + o);  o += (size_t)SCB * sizeof(int);

    zero_ints<<<(TOTC + 255) / 256, 256, 0, stream>>>(cnt, TOTC);
    bin_count2<<<(Nr + Nq + 255) / 256, 256, 0, stream>>>(ref, qp, cnt, Nr, Nq);
    scan1<<<SCB, 256, 0, stream>>>(cnt, off, bsum);
    scan2<<<SCB, 256, 0, stream>>>(bsum, off, cur, nflag);
    bin_fill2<<<(Nr + Nq + 255) / 256, 256, 0, stream>>>(ref, qp, cur, big, Nr, Nq);

    int nBlocks = (Nq + 7) / 8;                      // 8 sorted queries/block
    knn27<<<nBlocks, 256, 0, stream>>>(big, off, flow, out, qlist, nflag, Nr, Nq);
    brute_block<<<1024, 256, 0, stream>>>(qp, big, qlist, nflag, flow, out, Nr);
}

// Round 25
// 67.575 us; speedup vs baseline: 1.2702x; 1.0041x over previous
//
#include <hip/hip_runtime.h>
#include <math.h>

#define G      32
#define NCELLS (G * G * G)        // 32768
#define TOTC   (2 * NCELLS)       // ref cells + query cells
#define LOF    (-6.0f)
#define HH     0.375f             // 12/32
#define INVH   (1.0f / 0.375f)
#define DELTA  1e-3f              // accept slack >> fp d2 rounding (~1e-5)
#define R2ACC  (HH * HH)
#define SCB    256                // scan blocks (TOTC / 256)
#define SCC    (TOTC / SCB)       // 256 cells per scan block

__device__ __forceinline__ int cell_coord(float x) {
    int c = (int)floorf((x - LOF) * INVH);
    c = c < 0 ? 0 : c;
    return c > G - 1 ? G - 1 : c;
}
__device__ __forceinline__ int imax2(int a, int b) { return a > b ? a : b; }
__device__ __forceinline__ int imin2(int a, int b) { return a < b ? a : b; }
__device__ __forceinline__ float rdfl(float v) {
    return __int_as_float(__builtin_amdgcn_readfirstlane(__float_as_int(v)));
}

// lexicographic (d, idx) 3-slot insert == jax top_k tie semantics (order-free)
#define LEXINSERT(dv, jv) do {                                        \
    float d_ = (dv); int j_ = (jv);                                   \
    bool l0 = (d_ < e0) || ((d_ == e0) && (j_ < i0));                 \
    bool l1 = (d_ < e1) || ((d_ == e1) && (j_ < i1));                 \
    bool l2 = (d_ < e2) || ((d_ == e2) && (j_ < i2));                 \
    int   ni0 = l0 ? j_ : i0;                                         \
    int   ni1 = l0 ? i0 : (l1 ? j_ : i1);                             \
    int   ni2 = l1 ? i1 : (l2 ? j_ : i2);                             \
    float ne0 = l0 ? d_ : e0;                                         \
    float ne1 = l0 ? e0 : (l1 ? d_ : e1);                             \
    float ne2 = l1 ? e1 : (l2 ? d_ : e2);                             \
    e0 = ne0; e1 = ne1; e2 = ne2; i0 = ni0; i1 = ni1; i2 = ni2;       \
} while (0)

// masked body: out-of-range slots insert (INF, INT_MAX) — cannot displace
// under strict lex-less (proven R24 brute_block)
#define PBODY(rr_, uu_, lim_) do {                                    \
    float xx = (rr_).x * (rr_).x;                                     \
    float yy = (rr_).y * (rr_).y;                                     \
    float zz = (rr_).z * (rr_).z;                                     \
    float r2v = (xx + yy) + zz;                                       \
    float td = qx * (rr_).x;                                          \
    td = fmaf(qy, (rr_).y, td);                                       \
    td = fmaf(qz, (rr_).z, td);                                       \
    float aa = q2 + r2v;                                              \
    float dd = fmaf(-2.0f, td, aa);                                   \
    bool in_ = (uu_) < (lim_);                                        \
    dd = in_ ? dd : __builtin_inff();                                 \
    int jj = in_ ? __float_as_int((rr_).w) : 0x7fffffff;              \
    LEXINSERT(dd, jj);                                                \
} while (0)

// lanes split refs [lo,hi) of a contiguous run; coalesced float4 loads.
#define SCAN_RUN(lo_, hi_) do {                                       \
    for (int u = (lo_) + lane; u < (hi_); u += 64) {                  \
        float4 rr = srt[u];                                           \
        float xx = rr.x * rr.x;                                       \
        float yy = rr.y * rr.y;                                       \
        float zz = rr.z * rr.z;                                       \
        float r2 = (xx + yy) + zz;                                    \
        float td = qx * rr.x;                                         \
        td = fmaf(qy, rr.y, td);                                      \
        td = fmaf(qz, rr.z, td);                                      \
        float aa = q2 + r2;                                           \
        float dd = fmaf(-2.0f, td, aa);                               \
        int jj = __float_as_int(rr.w);                                \
        LEXINSERT(dd, jj);                                            \
    }                                                                 \
} while (0)

// 64-lane butterfly lex-merge of per-lane top-3 sets
#define MERGE64() do {                                                \
    _Pragma("unroll")                                                 \
    for (int mk_ = 1; mk_ < 64; mk_ <<= 1) {                          \
        float f0 = __shfl_xor(e0, mk_, 64);                           \
        float f1 = __shfl_xor(e1, mk_, 64);                           \
        float f2 = __shfl_xor(e2, mk_, 64);                           \
        int   g0 = __shfl_xor(i0, mk_, 64);                           \
        int   g1 = __shfl_xor(i1, mk_, 64);                           \
        int   g2 = __shfl_xor(i2, mk_, 64);                           \
        LEXINSERT(f0, g0);                                            \
        LEXINSERT(f1, g1);                                            \
        LEXINSERT(f2, g2);                                            \
    }                                                                 \
} while (0)

// 32-lane butterfly: both queries of the wave share the instructions
#define MERGE32() do {                                                \
    _Pragma("unroll")                                                 \
    for (int mk_ = 1; mk_ < 32; mk_ <<= 1) {                          \
        float f0 = __shfl_xor(e0, mk_, 64);                           \
        float f1 = __shfl_xor(e1, mk_, 64);                           \
        float f2 = __shfl_xor(e2, mk_, 64);                           \
        int   g0 = __shfl_xor(i0, mk_, 64);                           \
        int   g1 = __shfl_xor(i1, mk_, 64);                           \
        int   g2 = __shfl_xor(i2, mk_, 64);                           \
        LEXINSERT(f0, g0);                                            \
        LEXINSERT(f1, g1);                                            \
        LEXINSERT(f2, g2);                                            \
    }                                                                 \
} while (0)

// clamp + weights + gather + store, reference op order
#define EPILOGUE() do {                                               \
    e0 = fmaxf(e0, 0.0f);                                             \
    e1 = fmaxf(e1, 0.0f);                                             \
    e2 = fmaxf(e2, 0.0f);                                             \
    float s0 = sqrtf(e0);                                             \
    float s1 = sqrtf(e1);                                             \
    float s2 = sqrtf(e2);                                             \
    float w0 = 1.0f / (s0 + 1e-8f);                                   \
    float w1 = 1.0f / (s1 + 1e-8f);                                   \
    float w2 = 1.0f / (s2 + 1e-8f);                                   \
    float wsum = (w0 + w1) + w2;                                      \
    w0 = w0 / wsum; w1 = w1 / wsum; w2 = w2 / wsum;                   \
    float f0x = flow[i0*3+0], f0y = flow[i0*3+1], f0z = flow[i0*3+2]; \
    float f1x = flow[i1*3+0], f1y = flow[i1*3+1], f1z = flow[i1*3+2]; \
    float f2x = flow[i2*3+0], f2y = flow[i2*3+1], f2z = flow[i2*3+2]; \
    out[q*3+0] = (w0 * f0x + w1 * f1x) + w2 * f2x;                    \
    out[q*3+1] = (w0 * f0y + w1 * f1y) + w2 * f2y;                    \
    out[q*3+2] = (w0 * f0z + w1 * f1z) + w2 * f2z;                    \
} while (0)

__global__ __launch_bounds__(256) void zero_ints(int* __restrict__ p, int n) {
    int i = blockIdx.x * 256 + threadIdx.x;
    if (i < n) p[i] = 0;
}

// fused count: refs into cells [0,NCELLS), queries into [NCELLS, TOTC)
__global__ __launch_bounds__(256) void bin_count2(
    const float* __restrict__ ref, const float* __restrict__ qpts,
    int* __restrict__ cnt, int Nr, int Nq) {
    int j = blockIdx.x * 256 + threadIdx.x;
    if (j < Nr) {
        int cx = cell_coord(ref[3 * j + 0]);
        int cy = cell_coord(ref[3 * j + 1]);
        int cz = cell_coord(ref[3 * j + 2]);
        atomicAdd(&cnt[(cz * G + cy) * G + cx], 1);
    } else if (j < Nr + Nq) {
        int k = j - Nr;
        int cx = cell_coord(qpts[3 * k + 0]);
        int cy = cell_coord(qpts[3 * k + 1]);
        int cz = cell_coord(qpts[3 * k + 2]);
        atomicAdd(&cnt[NCELLS + (cz * G + cy) * G + cx], 1);
    }
}

// parallel hierarchical scan over TOTC cells (R20-proven structure)
__global__ __launch_bounds__(256) void scan1(
    const int* __restrict__ cnt, int* __restrict__ off, int* __restrict__ bsum) {
    __shared__ int wt[4];
    int tid = threadIdx.x, b = blockIdx.x;
    int base = b * SCC;
    int lane = tid & 63, wid = tid >> 6;
    int v = cnt[base + tid];
    int incl = v;
#pragma unroll
    for (int sh = 1; sh < 64; sh <<= 1) {
        int t = __shfl_up(incl, sh, 64);
        if (lane >= sh) incl += t;
    }
    if (lane == 63) wt[wid] = incl;
    __syncthreads();
    if (tid == 0) {
        int run = 0;
#pragma unroll
        for (int w = 0; w < 4; ++w) { int t = wt[w]; wt[w] = run; run += t; }
    }
    __syncthreads();
    int excl = wt[wid] + incl - v;
    off[base + tid] = excl;
    if (tid == SCC - 1) bsum[b] = excl + v;
}

// scan2 also zeroes the nflag counter (block 0)
__global__ __launch_bounds__(256) void scan2(
    const int* __restrict__ bsum, int* __restrict__ off, int* __restrict__ cur,
    int* __restrict__ nflag) {
    __shared__ int red[4];
    __shared__ int bo;
    int tid = threadIdx.x, b = blockIdx.x;
    int lane = tid & 63, wid = tid >> 6;
    if (b == 0 && tid == 0) nflag[0] = 0;
    int m = (tid < b) ? bsum[tid] : 0;             // b < SCB == 256
#pragma unroll
    for (int mk = 1; mk < 64; mk <<= 1) m += __shfl_xor(m, mk, 64);
    if (lane == 0) red[wid] = m;
    __syncthreads();
    if (tid == 0) bo = red[0] + red[1] + red[2] + red[3];
    __syncthreads();
    int boff = bo;
    int base = b * SCC;
    int t = off[base + tid] + boff;
    off[base + tid] = t;
    cur[base + tid] = t;
    if (b == SCB - 1 && tid == SCC - 1) off[TOTC] = boff + bsum[b];
}

// fused scatter: refs into big[0..Nr); queries into big[Nr..Nr+Nq)
__global__ __launch_bounds__(256) void bin_fill2(
    const float* __restrict__ ref, const float* __restrict__ qpts,
    int* __restrict__ cur, float4* __restrict__ big, int Nr, int Nq) {
    int j = blockIdx.x * 256 + threadIdx.x;
    if (j < Nr) {
        float x = ref[3 * j + 0], y = ref[3 * j + 1], z = ref[3 * j + 2];
        int cell = (cell_coord(z) * G + cell_coord(y)) * G + cell_coord(x);
        int pos = atomicAdd(&cur[cell], 1);
        big[pos] = make_float4(x, y, z, __int_as_float(j));
    } else if (j < Nr + Nq) {
        int k = j - Nr;
        float x = qpts[3 * k + 0], y = qpts[3 * k + 1], z = qpts[3 * k + 2];
        int cell = NCELLS + (cell_coord(z) * G + cell_coord(y)) * G + cell_coord(x);
        int pos = atomicAdd(&cur[cell], 1);
        big[pos] = make_float4(x, y, z, __int_as_float(k));
    }
}

// u -> srt index via the proven 9-row bijection (p*, b* group-uniform)
#define MAPIDX(u_, out_) do {                                         \
    int t_ = (u_) + b0;                                               \
    t_ = ((u_) >= p1) ? ((u_) + b1) : t_;                             \
    t_ = ((u_) >= p2) ? ((u_) + b2) : t_;                             \
    t_ = ((u_) >= p3) ? ((u_) + b3) : t_;                             \
    t_ = ((u_) >= p4) ? ((u_) + b4) : t_;                             \
    t_ = ((u_) >= p5) ? ((u_) + b5) : t_;                             \
    t_ = ((u_) >= p6) ? ((u_) + b6) : t_;                             \
    t_ = ((u_) >= p7) ? ((u_) + b7) : t_;                             \
    t_ = ((u_) >= p8) ? ((u_) + b8) : t_;                             \
    (out_) = t_;                                                      \
} while (0)

// ---------------------------------------------------------------------------
// 27-cell kNN over spatially sorted queries, MANUAL 4-DEEP PIPELINE in the
// scan loop (R24-proven pattern): map+clamp 4 indices, issue 4 independent
// gathers, then 4 masked bodies. Otherwise R22/R24-verbatim.
// ---------------------------------------------------------------------------
__global__ __launch_bounds__(256) void knn27(
    const float4* __restrict__ big, const int* __restrict__ off,
    const float* __restrict__ flow, float* __restrict__ out,
    int* __restrict__ qlist, int* __restrict__ nflag, int Nr, int Nq) {
#pragma clang fp contract(off)
    const float4* __restrict__ srt = big;          // refs region
    int sl = threadIdx.x & 31;                     // sub-lane in 32-group
    int sq = blockIdx.x * 8 + (threadIdx.x >> 5);  // sorted query index
    bool qv = sq < Nq;
    int sqc = qv ? sq : 0;

    float4 qq = big[(size_t)Nr + sqc];             // broadcast across group
    float qx = qq.x, qy = qq.y, qz = qq.z;
    int   q  = __float_as_int(qq.w);               // original query index
    float q2 = (qx * qx + qy * qy) + qz * qz;

    int cx = cell_coord(qx), cy = cell_coord(qy), cz = cell_coord(qz);

    int dz = sl / 3 - 1, dy = sl % 3 - 1;          // meaningful for sl<9
    int zr = cz + dz, yr = cy + dy;
    bool vrow = (sl < 9) && qv && (zr >= 0) && (zr < G) && (yr >= 0) && (yr < G);
    int xlo = imax2(cx - 1, 0), xhi = imin2(cx + 1, G - 1);
    int vlo = 0, vhi = 0;
    if (vrow) {
        int rowbase = (zr * G + yr) * G;
        vlo = off[rowbase + xlo];
        vhi = off[rowbase + xhi + 1];
    }
    int cnt = vhi - vlo;

    int incl = cnt;
#pragma unroll
    for (int sh = 1; sh <= 8; sh <<= 1) {
        int t = __shfl_up(incl, sh, 32);
        if (sl >= sh) incl += t;
    }
    int total = __shfl(incl, 8, 32);
    int prex  = incl - cnt;

    int p1 = __shfl(prex, 1, 32), p2 = __shfl(prex, 2, 32);
    int p3 = __shfl(prex, 3, 32), p4 = __shfl(prex, 4, 32);
    int p5 = __shfl(prex, 5, 32), p6 = __shfl(prex, 6, 32);
    int p7 = __shfl(prex, 7, 32), p8 = __shfl(prex, 8, 32);
    int b0 = __shfl(vlo, 0, 32);
    int b1 = __shfl(vlo, 1, 32) - p1;
    int b2 = __shfl(vlo, 2, 32) - p2;
    int b3 = __shfl(vlo, 3, 32) - p3;
    int b4 = __shfl(vlo, 4, 32) - p4;
    int b5 = __shfl(vlo, 5, 32) - p5;
    int b6 = __shfl(vlo, 6, 32) - p6;
    int b7 = __shfl(vlo, 7, 32) - p7;
    int b8 = __shfl(vlo, 8, 32) - p8;

    const float FINF = __builtin_inff();
    float e0 = FINF, e1 = FINF, e2 = FINF;
    int   i0 = 0x7fffffff, i1 = 0x7fffffff, i2 = 0x7fffffff;

    for (int ub = sl; ub < total; ub += 128) {
        int u0 = ub, u1 = ub + 32, u2 = ub + 64, u3 = ub + 96;
        int m1 = imin2(u1, total - 1);
        int m2 = imin2(u2, total - 1);
        int m3 = imin2(u3, total - 1);
        int x0, x1, x2, x3;
        MAPIDX(u0, x0);
        MAPIDX(m1, x1);
        MAPIDX(m2, x2);
        MAPIDX(m3, x3);
        float4 r0 = srt[x0];                       // 4 loads in flight
        float4 r1 = srt[x1];
        float4 r2 = srt[x2];
        float4 r3 = srt[x3];
        PBODY(r0, u0, total);
        PBODY(r1, u1, total);
        PBODY(r2, u2, total);
        PBODY(r3, u3, total);
    }

    MERGE32();

    bool ok = (e2 + DELTA < R2ACC);
    if (sl == 0 && qv) {
        if (ok) {
            EPILOGUE();
        } else {
            int pos = atomicAdd(nflag, 1);
            qlist[pos] = q;                        // original index
        }
    }
}

// ---------------------------------------------------------------------------
// Brute fallback (R24-passing verbatim): one block (4 waves) per flagged
// query, manual 4-deep pipeline, LDS cross-wave merge, wave-0 epilogue.
// ---------------------------------------------------------------------------
__global__ __launch_bounds__(256) void brute_block(
    const float* __restrict__ qpts, const float4* __restrict__ srt,
    const int* __restrict__ qlist, const int* __restrict__ nflag,
    const float* __restrict__ flow, float* __restrict__ out, int Nr) {
#pragma clang fp contract(off)
    __shared__ float sd[12];
    __shared__ int   si[12];
    int tid = threadIdx.x;
    int lane = tid & 63, wv = tid >> 6;
    int n = nflag[0];

    for (int f = blockIdx.x; f < n; f += gridDim.x) {
        int q = qlist[f];
        float qx = rdfl(qpts[3 * q + 0]);
        float qy = rdfl(qpts[3 * q + 1]);
        float qz = rdfl(qpts[3 * q + 2]);
        float q2 = (qx * qx + qy * qy) + qz * qz;

        int CS = (Nr + 3) / 4;
        int lo = wv * CS;
        int hi = imin2(lo + CS, Nr);

        const float FINF = __builtin_inff();
        float e0 = FINF, e1 = FINF, e2 = FINF;
        int   i0 = 0x7fffffff, i1 = 0x7fffffff, i2 = 0x7fffffff;

        for (int ub = lo + lane; ub < hi; ub += 256) {
            int u0 = ub, u1 = ub + 64, u2 = ub + 128, u3 = ub + 192;
            float4 r0 = srt[imin2(u0, hi - 1)];
            float4 r1 = srt[imin2(u1, hi - 1)];
            float4 r2 = srt[imin2(u2, hi - 1)];
            float4 r3 = srt[imin2(u3, hi - 1)];
            PBODY(r0, u0, hi);
            PBODY(r1, u1, hi);
            PBODY(r2, u2, hi);
            PBODY(r3, u3, hi);
        }

        MERGE64();

        if (lane == 0) {
            sd[wv * 3 + 0] = e0; si[wv * 3 + 0] = i0;
            sd[wv * 3 + 1] = e1; si[wv * 3 + 1] = i1;
            sd[wv * 3 + 2] = e2; si[wv * 3 + 2] = i2;
        }
        __syncthreads();
        if (wv == 0) {
            e0 = e1 = e2 = FINF;
            i0 = i1 = i2 = 0x7fffffff;
            if (lane < 12) { e0 = sd[lane]; i0 = si[lane]; }
            MERGE64();
            if (lane == 0) EPILOGUE();
        }
        __syncthreads();
    }
}

extern "C" void kernel_launch(void* const* d_in, const int* in_sizes, int n_in,
                              void* d_out, int out_size, void* d_ws, size_t ws_size,
                              hipStream_t stream) {
    const float* qp   = (const float*)d_in[0];
    const float* ref  = (const float*)d_in[1];
    const float* flow = (const float*)d_in[2];
    float* out = (float*)d_out;

    int Nq = in_sizes[0] / 3;
    int Nr = in_sizes[1] / 3;

    char* ws = (char*)d_ws;
    float4* big = (float4*)ws;                       // (Nr+Nq) float4
    size_t o = (size_t)(Nr + Nq) * sizeof(float4);
    int* off    = (int*)(ws + o);  o += (size_t)(TOTC + 1) * sizeof(int);
    int* cur    = (int*)(ws + o);  o += (size_t)TOTC * sizeof(int);
    int* cnt    = (int*)(ws + o);  o += (size_t)TOTC * sizeof(int);
    int* nflag  = (int*)(ws + o);  o += sizeof(int); // zeroed by scan2
    int* qlist  = (int*)(ws + o);  o += (size_t)Nq * sizeof(int);
    int* bsum   = (int*)(ws + o);  o += (size_t)SCB * sizeof(int);

    zero_ints<<<(TOTC + 255) / 256, 256, 0, stream>>>(cnt, TOTC);
    bin_count2<<<(Nr + Nq + 255) / 256, 256, 0, stream>>>(ref, qp, cnt, Nr, Nq);
    scan1<<<SCB, 256, 0, stream>>>(cnt, off, bsum);
    scan2<<<SCB, 256, 0, stream>>>(bsum, off, cur, nflag);
    bin_fill2<<<(Nr + Nq + 255) / 256, 256, 0, stream>>>(ref, qp, cur, big, Nr, Nq);

    int nBlocks = (Nq + 7) / 8;                      // 8 sorted queries/block
    knn27<<<nBlocks, 256, 0, stream>>>(big, off, flow, out, qlist, nflag, Nr, Nq);
    brute_block<<<1024, 256, 0, stream>>>(qp, big, qlist, nflag, flow, out, Nr);
}